// Round 2
// baseline (2047.147 us; speedup 1.0000x reference)
//
#include <hip/hip_runtime.h>

typedef __bf16 bf16x8 __attribute__((ext_vector_type(8)));
typedef float f32x4 __attribute__((ext_vector_type(4)));
typedef unsigned short u16;
typedef unsigned int u32;

#define D_DIM 4096
#define B_ROWS 16384
#define K_CLS 14
#define M_TOT 32768
#define BK 64

// ---------- helpers ----------
__device__ __forceinline__ u32 f2bf(float f) {
    u32 u = __float_as_uint(f);
    return (u + 0x7FFFu + ((u >> 16) & 1u)) >> 16;   // RNE
}
__device__ __forceinline__ float bfl(u32 u) { return __uint_as_float(u << 16); }
__device__ __forceinline__ float bfh(u32 u) { return __uint_as_float(u & 0xFFFF0000u); }

typedef __attribute__((address_space(3))) void lds_void;
typedef __attribute__((address_space(1))) void glb_void;

__device__ __forceinline__ void g2lds16(const void* g, void* l) {
    __builtin_amdgcn_global_load_lds(
        reinterpret_cast<glb_void*>(reinterpret_cast<uintptr_t>(g)),
        reinterpret_cast<lds_void*>(reinterpret_cast<uintptr_t>(l)),
        16, 0, 0);
}

// ---------- merged cast f32 -> bf16 for image, text, Wv, Wt ----------
// dst: Xbf[32768][4096] followed by Wbf[2][4096][4096] (contiguous in ws)
__global__ void cast_all(const float* __restrict__ im, const float* __restrict__ tx,
                         const float* __restrict__ wv, const float* __restrict__ wt,
                         u16* __restrict__ dst) {
    const int C1 = 16777216;            // image f4 count
    const int C2 = 33554432;            // + text
    const int C3 = 37748736;            // + Wv
    const int C4 = 41943040;            // + Wt
    int i = blockIdx.x * blockDim.x + threadIdx.x;
    const int stride = gridDim.x * blockDim.x;
    for (; i < C4; i += stride) {
        const float4* s; int j;
        if (i < C1)      { s = (const float4*)im; j = i; }
        else if (i < C2) { s = (const float4*)tx; j = i - C1; }
        else if (i < C3) { s = (const float4*)wv; j = i - C2; }
        else             { s = (const float4*)wt; j = i - C3; }
        float4 a = s[j];
        uint2 o;
        o.x = f2bf(a.x) | (f2bf(a.y) << 16);
        o.y = f2bf(a.z) | (f2bf(a.w) << 16);
        ((uint2*)dst)[i] = o;
    }
}

// ---------- prototype normalize + passthrough copy ----------
// pTbf layout: [D][16] bf16 (k-major inner, pad 14->16)
__global__ void proto_norm(const float* __restrict__ P, u16* __restrict__ pTbf,
                           float* __restrict__ outProto) {
    const int k = blockIdx.x;
    const int tid = threadIdx.x;
    float ss = 0.f;
    for (int d = tid; d < D_DIM; d += 256) {
        float v = P[k * D_DIM + d];
        ss += v * v;
    }
    for (int off = 32; off; off >>= 1) ss += __shfl_down(ss, off);
    __shared__ float red[4];
    if ((tid & 63) == 0) red[tid >> 6] = ss;
    __syncthreads();
    float tot = red[0] + red[1] + red[2] + red[3];
    float inv = 1.0f / fmaxf(sqrtf(tot), 1e-12f);
    for (int d = tid; d < D_DIM; d += 256) {
        float v = P[k * D_DIM + d];
        outProto[k * D_DIM + d] = v;                       // exact passthrough
        pTbf[(size_t)d * 16 + k] = (u16)f2bf(v * inv);
    }
}

// ---------- batch co-occurrence ----------
__global__ void cooccur_bc(const int* __restrict__ L, float* __restrict__ bc) {
    const int i = blockIdx.x / K_CLS, j = blockIdx.x % K_CLS;
    int s = 0;
    for (int b = threadIdx.x; b < B_ROWS; b += 256)
        s += L[b * K_CLS + i] * L[b * K_CLS + j];
    for (int off = 32; off; off >>= 1) s += __shfl_down(s, off);
    __shared__ int red[4];
    if ((threadIdx.x & 63) == 0) red[threadIdx.x >> 6] = s;
    __syncthreads();
    if (threadIdx.x == 0)
        bc[blockIdx.x] = (float)(red[0] + red[1] + red[2] + red[3]) / (float)B_ROWS;
}

__global__ void cooccur_loss(const float* __restrict__ C, const float* __restrict__ bc,
                             float* __restrict__ out) {
    const int t = threadIdx.x;
    float d2 = 0.f;
    if (t < K_CLS * K_CLS) {
        float s = 1.0f / (1.0f + expf(-C[t]));
        float d = s - bc[t];
        d2 = d * d;
    }
    for (int off = 32; off; off >>= 1) d2 += __shfl_down(d2, off);
    __shared__ float red[4];
    if ((t & 63) == 0) red[t >> 6] = d2;
    __syncthreads();
    if (t == 0) out[0] = (red[0] + red[1] + red[2] + red[3]) / (float)(K_CLS * K_CLS);
}

// ---------- bf16 GEMM-BT, BK=64, XOR-swizzled LDS ----------
// LDS row = 128 B (64 u16) = 8 chunks of 16 B. Chunk c of row r is stored at
// position c ^ (r&7). Writer (global_load_lds forces LDS slot = base+lane*16)
// permutes the GLOBAL source chunk instead; reader applies quad ^ (mlane&7).
// Quarter-wave then covers all 8 bank-groups 2-way -> conflict-free (m136).
__global__ __launch_bounds__(256) void gemm_bt(
    const u16* __restrict__ Xbf,   // [32768][4096]
    const u16* __restrict__ Wbf,   // [2][4096][4096]
    const float* __restrict__ bv, const float* __restrict__ bt,
    u16* __restrict__ Ybf)         // [32768][4096]
{
    __shared__ __align__(16) u16 As[128 * BK];   // 16 KB
    __shared__ __align__(16) u16 Bs[128 * BK];   // 16 KB

    const int tid = threadIdx.x;
    const int wave = tid >> 6, lane = tid & 63;
    const int bn0 = blockIdx.x * 128;
    const int bm0 = blockIdx.y * 128;
    const int half = (bm0 >= B_ROWS) ? 1 : 0;
    const u16* Wsel = Wbf + (size_t)half * D_DIM * D_DIM;
    const float* bias = half ? bt : bv;

    // staging: one 1KB group = 8 rows x 128B. lane -> row lane>>3, chunk-pos lane&7
    const int srow = lane >> 3;                      // 0..7
    const int gcol = ((lane & 7) ^ srow) * 8;        // swizzled global u16 col
    const u16* Ag = Xbf + (size_t)bm0 * D_DIM;
    const u16* Bg = Wsel + (size_t)bn0 * D_DIM;
    const u16* gA[4]; const u16* gB[4];
    u16* lA[4]; u16* lB[4];
#pragma unroll
    for (int i = 0; i < 4; i++) {
        const int g = wave * 4 + i;                  // group 0..15
        const int row = g * 8 + srow;
        gA[i] = Ag + (size_t)row * D_DIM + gcol;
        gB[i] = Bg + (size_t)row * D_DIM + gcol;
        lA[i] = &As[g * 512];
        lB[i] = &Bs[g * 512];
    }

    const int waveM = wave >> 1, waveN = wave & 1;
    const int mlane = lane & 15, quad = lane >> 4;
    const int sw0 = (quad ^ (mlane & 7)) * 8;        // k-step 0 chunk pos (u16 units)
    const int sw1 = sw0 ^ 32;                        // k-step 1: chunk ^ 4
    const u16* Ar0 = &As[(waveM * 64 + mlane) * BK + sw0];
    const u16* Br0 = &Bs[(waveN * 64 + mlane) * BK + sw0];
    const u16* Ar1 = &As[(waveM * 64 + mlane) * BK + sw1];
    const u16* Br1 = &Bs[(waveN * 64 + mlane) * BK + sw1];

    f32x4 acc[4][4] = {};

    for (int k0 = 0; k0 < D_DIM; k0 += BK) {
        __syncthreads();                 // prev tile's ds_reads done
#pragma unroll
        for (int i = 0; i < 4; i++) g2lds16(gA[i] + k0, lA[i]);
#pragma unroll
        for (int i = 0; i < 4; i++) g2lds16(gB[i] + k0, lB[i]);
        __syncthreads();                 // staged data visible
        bf16x8 a[4], b[4];
        // k-step 0: global cols k0 + quad*8
#pragma unroll
        for (int mi = 0; mi < 4; mi++) a[mi] = *(const bf16x8*)(Ar0 + mi * 16 * BK);
#pragma unroll
        for (int ni = 0; ni < 4; ni++) b[ni] = *(const bf16x8*)(Br0 + ni * 16 * BK);
#pragma unroll
        for (int mi = 0; mi < 4; mi++)
#pragma unroll
            for (int ni = 0; ni < 4; ni++)
                acc[mi][ni] = __builtin_amdgcn_mfma_f32_16x16x32_bf16(
                    a[mi], b[ni], acc[mi][ni], 0, 0, 0);
        // k-step 1: global cols k0 + 32 + quad*8
#pragma unroll
        for (int mi = 0; mi < 4; mi++) a[mi] = *(const bf16x8*)(Ar1 + mi * 16 * BK);
#pragma unroll
        for (int ni = 0; ni < 4; ni++) b[ni] = *(const bf16x8*)(Br1 + ni * 16 * BK);
#pragma unroll
        for (int mi = 0; mi < 4; mi++)
#pragma unroll
            for (int ni = 0; ni < 4; ni++)
                acc[mi][ni] = __builtin_amdgcn_mfma_f32_16x16x32_bf16(
                    a[mi], b[ni], acc[mi][ni], 0, 0, 0);
    }

    // epilogue: C/D layout col=lane&15, row=quad*4+reg
#pragma unroll
    for (int ni = 0; ni < 4; ni++) {
        const int col = bn0 + waveN * 64 + ni * 16 + mlane;
        const float bcol = bias[col];
#pragma unroll
        for (int mi = 0; mi < 4; mi++) {
            f32x4 v = acc[mi][ni];
#pragma unroll
            for (int r = 0; r < 4; r++) {
                const int row = bm0 + waveM * 64 + mi * 16 + quad * 4 + r;
                Ybf[(size_t)row * D_DIM + col] = (u16)f2bf(v[r] + bcol);
            }
        }
    }
}

// ---------- sim + norm: sim[r][k] = (y_r . p_hat_k) / max(||y_r||, eps) ----------
__global__ __launch_bounds__(256) void simproj(
    const u16* __restrict__ Ybf, const u16* __restrict__ pTbf,
    float* __restrict__ sim)
{
    const int tid = threadIdx.x;
    const int wave = tid >> 6, lane = tid & 63;
    const int r0 = blockIdx.x * 16 + wave * 4;
    const u16* Y0 = Ybf + (size_t)r0 * D_DIM;

    float acc[4][15];
#pragma unroll
    for (int r = 0; r < 4; r++)
#pragma unroll
        for (int k = 0; k < 15; k++) acc[r][k] = 0.f;

#pragma unroll 2
    for (int i = 0; i < 64; i++) {
        const int d = lane + i * 64;
        const uint4* pq = (const uint4*)(pTbf + (size_t)d * 16);
        const uint4 q0 = pq[0], q1 = pq[1];
        const float p[14] = { bfl(q0.x), bfh(q0.x), bfl(q0.y), bfh(q0.y),
                              bfl(q0.z), bfh(q0.z), bfl(q0.w), bfh(q0.w),
                              bfl(q1.x), bfh(q1.x), bfl(q1.y), bfh(q1.y),
                              bfl(q1.z), bfh(q1.z) };
#pragma unroll
        for (int r = 0; r < 4; r++) {
            const float yv = bfl((u32)Y0[(size_t)r * D_DIM + d]);
            acc[r][14] += yv * yv;
#pragma unroll
            for (int k = 0; k < 14; k++) acc[r][k] += yv * p[k];
        }
    }
#pragma unroll
    for (int r = 0; r < 4; r++)
#pragma unroll
        for (int k = 0; k < 15; k++) {
            float v = acc[r][k];
            v += __shfl_xor(v, 1);  v += __shfl_xor(v, 2);  v += __shfl_xor(v, 4);
            v += __shfl_xor(v, 8);  v += __shfl_xor(v, 16); v += __shfl_xor(v, 32);
            acc[r][k] = v;
        }
    if (lane == 0) {
#pragma unroll
        for (int r = 0; r < 4; r++) {
            const float inv = 1.0f / fmaxf(sqrtf(acc[r][14]), 1e-12f);
#pragma unroll
            for (int k = 0; k < 14; k++)
                sim[(size_t)(r0 + r) * K_CLS + k] = acc[r][k] * inv;
        }
    }
}

// ---------- final: shapley = 0.5*(v_sim + t_sim)*label ----------
__global__ void finalize(const float* __restrict__ sim, const int* __restrict__ L,
                         float* __restrict__ out) {
    const int t = blockIdx.x * 256 + threadIdx.x;
    if (t >= B_ROWS * K_CLS) return;
    out[t] = 0.5f * (sim[t] + sim[t + B_ROWS * K_CLS]) * (float)L[t];
}

// ---------- launch ----------
extern "C" void kernel_launch(void* const* d_in, const int* in_sizes, int n_in,
                              void* d_out, int out_size, void* d_ws, size_t ws_size,
                              hipStream_t stream) {
    const float* image  = (const float*)d_in[0];
    const float* text   = (const float*)d_in[1];
    const int*   labels = (const int*)d_in[2];
    const float* bv     = (const float*)d_in[4];
    const float* bt     = (const float*)d_in[6];
    const float* protos = (const float*)d_in[7];
    const float* cooc   = (const float*)d_in[8];
    float* out = (float*)d_out;

    // workspace layout (bytes) — Xbf and Wbf contiguous (cast_all assumes it)
    const size_t OFF_X   = 0;                       // 268,435,456
    const size_t OFF_W   = 268435456ull;            //  67,108,864
    const size_t OFF_Y   = 335544320ull;            // 268,435,456
    const size_t OFF_PT  = 603979776ull;            //     131,072
    const size_t OFF_SIM = 604110848ull;            //   1,835,008
    const size_t OFF_BC  = 605945856ull;            //         784
    const size_t NEED    = 605946640ull;
    if (ws_size < NEED) return;

    char* ws = (char*)d_ws;
    u16*   Xbf  = (u16*)(ws + OFF_X);
    u16*   Wbf  = (u16*)(ws + OFF_W);
    u16*   Ybf  = (u16*)(ws + OFF_Y);
    u16*   pTbf = (u16*)(ws + OFF_PT);
    float* sim  = (float*)(ws + OFF_SIM);
    float* bc   = (float*)(ws + OFF_BC);

    // one merged cast for image, text, Wv, Wt
    cast_all<<<8192, 256, 0, stream>>>(image, text,
                                       (const float*)d_in[3], (const float*)d_in[5], Xbf);

    // small side computations
    proto_norm<<<K_CLS, 256, 0, stream>>>(protos, pTbf, out + B_ROWS * K_CLS);
    cooccur_bc<<<K_CLS * K_CLS, 256, 0, stream>>>(labels, bc);
    cooccur_loss<<<1, 256, 0, stream>>>(cooc, bc, out + B_ROWS * K_CLS + K_CLS * D_DIM);

    // main GEMM
    gemm_bt<<<dim3(D_DIM / 128, M_TOT / 128), 256, 0, stream>>>(Xbf, Wbf, bv, bt, Ybf);

    // projection + normalization
    simproj<<<M_TOT / 16, 256, 0, stream>>>(Ybf, pTbf, sim);

    // combine halves with labels
    finalize<<<(B_ROWS * K_CLS + 255) / 256, 256, 0, stream>>>(sim, labels, out);
}